// Round 3
// baseline (1002.396 us; speedup 1.0000x reference)
//
#include <hip/hip_runtime.h>

// NNGLS: y_decor, o_decor, o for N=200000, M=20, MLP 64->256->1.
//
// K1 (mlp_mfma_kernel): split-bf16 MFMA GEMM (x=xh+xl, w1=wh+wl; 3 passes
//     ah*bh + al*bh + ah*bl => ~fp32 accuracy). Wave owns 64 nodes (4 M-tiles
//     of mfma_f32_16x16x32_bf16); w1 staged frag-ordered in LDS (hi+lo, 64KB);
//     layer2 (relu->dot w2) fused via per-lane partials + shfl_xor reduction.
//     UNCHANGED this round (control) -- next round it surfaces in top-5.
// K2 (solve_kernel): QUAD-SPLIT bordered 21x21 elimination.
//     Node i is handled by a 4-lane quad; lane h = tid&3 owns matrix columns
//     c === h (mod 4) in padded flat storage cs[81]:
//       slot j=0..4 : column c = 4j+h, padded rows 0..4j+3 (offset 2j(j+1))
//       slot 5      : column 20 REPLICATED on all lanes (offset 60, rows 0..20)
//     -> ~81 matrix regs/lane (vs 231 single-lane / 131 pair-split). Peak live
//     set ~160 floats + temps -> fits the 256-reg cap of launch_bounds(256,2)
//     with headroom (round-2 lesson: no headroom => allocator spills the whole
//     array to scratch, 2.5 GB traffic). Per step k: 1 shfl pivot broadcast,
//     (19-k) quad shfls exchange multipliers m[r]=a[k][r]*rp (computed on the
//     column owner), then each lane updates its own columns + replicated c20 +
//     its border vector (lanes 0,2: y; lanes 1,3: o). Identical FMA sequence
//     per real entry => bit-identical results. Junk padded entries are real
//     covariance values (finite), written but never read for outputs.
//     All register-array indices are compile-time (col coords gathered
//     directly from nbr/pos to avoid runtime-indexing a register array).

#define MM   20
#define PP   64
#define HH   256
#define EPSF 1e-12f

// flat quad-split storage: slot j (col 4j+h), padded rows 0..4j+3
#define CSE(j, r) csx[2*(j)*((j)+1) + (r)]
#define C20(r)    csx[60 + (r)]

typedef __attribute__((ext_vector_type(8))) short bf16x8;
typedef __attribute__((ext_vector_type(4))) float f32x4;

static __device__ __forceinline__ unsigned short f2bf(float f) {
    unsigned int u = __builtin_bit_cast(unsigned int, f);
    u += 0x7fffu + ((u >> 16) & 1u);          // RNE
    return (unsigned short)(u >> 16);
}
static __device__ __forceinline__ float bf2f(unsigned short h) {
    unsigned int u = ((unsigned int)h) << 16;
    return __builtin_bit_cast(float, u);
}

__global__ __launch_bounds__(256, 2)
void mlp_mfma_kernel(const float* __restrict__ x,
                     const float* __restrict__ w1,
                     const float* __restrict__ b1,
                     const float* __restrict__ w2,
                     const float* __restrict__ b2,
                     float* __restrict__ o_out, int n)
{
    __shared__ __align__(16) short swh[PP * HH];   // 32 KB  w1 hi, frag order
    __shared__ __align__(16) short swl[PP * HH];   // 32 KB  w1 lo
    const int tid = threadIdx.x;

    // ---- stage w1 -> frag-ordered bf16 hi/lo ----
    {
        const int col = tid;                       // 256 cols, one per thread
        const int t = col >> 4, nn = col & 15;
        #pragma unroll
        for (int g = 0; g < 8; ++g) {              // k = g*8 + u
            const int s = g >> 2, q = g & 3;
            bf16x8 hv, lv;
            #pragma unroll
            for (int u = 0; u < 8; ++u) {
                float v = w1[(g * 8 + u) * HH + col];
                unsigned short h = f2bf(v);
                hv[u] = (short)h;
                lv[u] = (short)f2bf(v - bf2f(h));
            }
            const int base = ((((t * 2 + s) * 4 + q) * 16) + nn) * 8;
            *(bf16x8*)&swh[base] = hv;
            *(bf16x8*)&swl[base] = lv;
        }
    }
    __syncthreads();

    const int lane = tid & 63;
    const int wv   = tid >> 6;
    const int nn   = lane & 15;      // A-row (node) / B-col (hidden) / C-col
    const int q    = lane >> 4;      // quad
    const int wb   = blockIdx.x * 256 + wv * 64;   // first node of this wave

    float w2v[16], b1v[16];
    #pragma unroll
    for (int t = 0; t < 16; ++t) {
        w2v[t] = w2[t * 16 + nn];
        b1v[t] = b1[t * 16 + nn];
    }

    // ---- A fragments: 4 M-tiles x 2 k-steps, split hi/lo ----
    bf16x8 ah[4][2], al[4][2];
    #pragma unroll
    for (int mt = 0; mt < 4; ++mt) {
        const int row = wb + mt * 16 + nn;
        #pragma unroll
        for (int s = 0; s < 2; ++s) {
            float v[8];
            if (row < n) {
                const float* xp = x + (size_t)row * PP + s * 32 + q * 8;
                float4 va = *(const float4*)(xp);
                float4 vb = *(const float4*)(xp + 4);
                v[0]=va.x; v[1]=va.y; v[2]=va.z; v[3]=va.w;
                v[4]=vb.x; v[5]=vb.y; v[6]=vb.z; v[7]=vb.w;
            } else {
                #pragma unroll
                for (int u = 0; u < 8; ++u) v[u] = 0.0f;
            }
            bf16x8 h, l;
            #pragma unroll
            for (int u = 0; u < 8; ++u) {
                unsigned short hb = f2bf(v[u]);
                h[u] = (short)hb;
                l[u] = (short)f2bf(v[u] - bf2f(hb));
            }
            ah[mt][s] = h;
            al[mt][s] = l;
        }
    }

    float part[4][4];
    #pragma unroll
    for (int mt = 0; mt < 4; ++mt)
        #pragma unroll
        for (int r = 0; r < 4; ++r) part[mt][r] = 0.0f;

    #pragma unroll
    for (int t = 0; t < 16; ++t) {
        f32x4 acc[4];
        #pragma unroll
        for (int mt = 0; mt < 4; ++mt) acc[mt] = (f32x4)(0.0f);
        #pragma unroll
        for (int s = 0; s < 2; ++s) {
            const int fb = ((((t * 2 + s) * 4 + q) * 16) + nn) * 8;
            bf16x8 bh = *(const bf16x8*)&swh[fb];
            bf16x8 bl = *(const bf16x8*)&swl[fb];
            #pragma unroll
            for (int mt = 0; mt < 4; ++mt) {
                acc[mt] = __builtin_amdgcn_mfma_f32_16x16x32_bf16(ah[mt][s], bh, acc[mt], 0, 0, 0);
                acc[mt] = __builtin_amdgcn_mfma_f32_16x16x32_bf16(al[mt][s], bh, acc[mt], 0, 0, 0);
                acc[mt] = __builtin_amdgcn_mfma_f32_16x16x32_bf16(ah[mt][s], bl, acc[mt], 0, 0, 0);
            }
        }
        #pragma unroll
        for (int mt = 0; mt < 4; ++mt)
            #pragma unroll
            for (int r = 0; r < 4; ++r)
                part[mt][r] = fmaf(fmaxf(acc[mt][r] + b1v[t], 0.0f), w2v[t], part[mt][r]);
    }

    #pragma unroll
    for (int w = 1; w < 16; w <<= 1)
        #pragma unroll
        for (int mt = 0; mt < 4; ++mt)
            #pragma unroll
            for (int r = 0; r < 4; ++r)
                part[mt][r] += __shfl_xor(part[mt][r], w, 64);

    const float bb = b2[0];
    if (nn == 0) {
        #pragma unroll
        for (int mt = 0; mt < 4; ++mt) {
            const int row = wb + mt * 16 + q * 4;   // rows q*4+reg, reg=0..3
            if (row < n) {
                float4 o4 = make_float4(part[mt][0] + bb, part[mt][1] + bb,
                                        part[mt][2] + bb, part[mt][3] + bb);
                *(float4*)&o_out[row] = o4;
            }
        }
    }
}

__global__ __launch_bounds__(256, 2)
void solve_kernel(const float* __restrict__ pos,
                  const float* __restrict__ y,
                  const int*   __restrict__ nbr,
                  const float* __restrict__ theta,
                  const float* __restrict__ o_in,
                  float* __restrict__ yd,
                  float* __restrict__ od, int n)
{
    const int tid  = threadIdx.x;
    const int l6   = tid & 63;             // lane within wave
    const int h_   = tid & 3;              // column class this lane owns
    const int i    = (blockIdx.x * 256 + tid) >> 2;   // node (4 lanes share)
    if (i >= n) return;
    const int qb   = l6 & ~3;              // quad base lane

    const float sigma_sq = theta[0];
    const float phi      = theta[1];
    const float tau      = theta[2];
    const float tau_sq   = tau * sigma_sq;

    const float L2E = 1.44269504088896340736f;
    const float c1  = -phi * L2E;                       // exp(-phi*d) = exp2(c1*d)
    const float c0  = __builtin_amdgcn_logf(sigma_sq);  // log2(sigma^2)

    const float sqrtEPS = __builtin_amdgcn_sqrtf(EPSF);
    const float diagA   = __builtin_amdgcn_exp2f(fmaf(sqrtEPS, c1, c0)) + tau_sq;
    const float diagB   = sigma_sq + tau;               // border diagonal

    // ---- neighbor indices (static array, static indices only) ----
    int idx[MM];
    const int4* nb4 = (const int4*)(nbr + (size_t)i * MM);
    #pragma unroll
    for (int k = 0; k < MM / 4; ++k) {
        int4 v = nb4[k];
        idx[4*k] = v.x; idx[4*k+1] = v.y; idx[4*k+2] = v.z; idx[4*k+3] = v.w;
    }

    // row coords (all 21, static-indexed)
    float px[21], py[21];
    const float2* pos2 = (const float2*)pos;
    #pragma unroll
    for (int j = 0; j < MM; ++j) {
        float2 p = pos2[idx[j]];
        px[j] = p.x; py[j] = p.y;
    }
    {
        float2 p = pos2[i];
        px[20] = p.x; py[20] = p.y;
    }

    // my columns' coords: gathered DIRECTLY from nbr/pos (runtime address is
    // fine; runtime index into a register array is not).
    float cx[5], cy[5];
    #pragma unroll
    for (int j = 0; j < 5; ++j) {
        int cj = nbr[(size_t)i * MM + 4*j + h_];
        float2 p = pos2[cj];
        cx[j] = p.x; cy[j] = p.y;
    }

    // border vector: lanes 0,2 carry y; lanes 1,3 carry o
    float bv[21];
    {
        const float* src = (h_ & 1) ? o_in : y;
        #pragma unroll
        for (int j = 0; j < MM; ++j) bv[j] = src[idx[j]];
        bv[20] = src[i];
    }

    // ---- build my columns (padded) + replicated column 20 ----
    float csx[81];
    #pragma unroll
    for (int j = 0; j < 5; ++j) {
        #pragma unroll
        for (int r = 0; r <= 4*j + 3; ++r) {
            float dx = px[r] - cx[j];
            float dy = py[r] - cy[j];
            float d  = __builtin_amdgcn_sqrtf(fmaf(dx, dx, fmaf(dy, dy, EPSF)));
            float v  = __builtin_amdgcn_exp2f(fmaf(d, c1, c0));
            v = (r == 4*j + h_) ? diagA : v;       // diagonal entry of col c
            CSE(j, r) = v;
        }
    }
    #pragma unroll
    for (int r = 0; r <= 20; ++r) {
        if (r == 20) {
            C20(20) = diagB;
        } else {
            float dx = px[r] - px[20];
            float dy = py[r] - py[20];
            float d  = __builtin_amdgcn_sqrtf(fmaf(dx, dx, fmaf(dy, dy, EPSF)));
            C20(r)   = __builtin_amdgcn_exp2f(fmaf(d, c1, c0));
        }
    }

    // ---- 20 elimination steps, quad-cooperative ----
    #pragma unroll
    for (int k = 0; k < 20; ++k) {
        // pivot broadcast from owner lane (k&3), slot k>>2, row k
        float pdl = CSE(k >> 2, k);                // padded row k always exists
        float pd  = __shfl(pdl, qb + (k & 3), 64);
        float rp = __builtin_amdgcn_rcpf(pd);
        rp = rp * (2.0f - pd * rp);                // Newton refine

        // local multipliers for my column slots (valid where row k is stored)
        float mv[5];
        #pragma unroll
        for (int j = 0; j < 5; ++j)
            if (4*j + 3 >= k) mv[j] = CSE(j, k) * rp;

        // gather all multipliers m[r] = a[k][r]*rp from column owners
        float m_all[21];
        #pragma unroll
        for (int r = k + 1; r <= 19; ++r)
            m_all[r] = __shfl(mv[r >> 2], qb + (r & 3), 64);
        m_all[20] = C20(k) * rp;                   // col 20 replicated locally

        // rank-1 update: my columns
        #pragma unroll
        for (int j = 0; j < 5; ++j) {
            if (4*j + 3 > k) {
                float pk = CSE(j, k);
                #pragma unroll
                for (int r = k + 1; r <= 4*j + 3; ++r)
                    CSE(j, r) = fmaf(-m_all[r], pk, CSE(j, r));
            }
        }
        // replicated column 20
        {
            float p20 = C20(k);
            #pragma unroll
            for (int r = k + 1; r <= 20; ++r)
                C20(r) = fmaf(-m_all[r], p20, C20(r));
        }
        // border vector
        {
            float bk = bv[k];
            #pragma unroll
            for (int r = k + 1; r <= 20; ++r)
                bv[r] = fmaf(-m_all[r], bk, bv[r]);
        }
    }

    // f = a[20][20], replicated on every lane
    float f  = C20(20);
    float is = __builtin_amdgcn_rsqf(f);
    is = is * fmaf(-0.5f * f * is, is, 1.5f);

    if (h_ == 0)      yd[i] = bv[20] * is;   // lane 0 carries y
    else if (h_ == 1) od[i] = bv[20] * is;   // lane 1 carries o
}

extern "C" void kernel_launch(void* const* d_in, const int* in_sizes, int n_in,
                              void* d_out, int out_size, void* d_ws, size_t ws_size,
                              hipStream_t stream)
{
    const float* x     = (const float*)d_in[0];
    const float* pos   = (const float*)d_in[1];
    const float* y     = (const float*)d_in[2];
    const int*   nbr   = (const int*)  d_in[3];
    const float* theta = (const float*)d_in[4];
    const float* w1    = (const float*)d_in[5];
    const float* b1    = (const float*)d_in[6];
    const float* w2    = (const float*)d_in[7];
    const float* b2    = (const float*)d_in[8];

    const int n = in_sizes[2];                 // N
    float* out = (float*)d_out;
    float* yd = out;
    float* od = out + (size_t)n;
    float* oo = out + 2 * (size_t)n;

    mlp_mfma_kernel<<<(n + 255) / 256, 256, 0, stream>>>(x, w1, b1, w2, b2, oo, n);
    // 64 nodes per 256-thread block (4 lanes per node)
    solve_kernel<<<(n + 63) / 64, 256, 0, stream>>>(pos, y, nbr, theta, oo, yd, od, n);
}

// Round 4
// 312.864 us; speedup vs baseline: 3.2039x; 3.2039x over previous
//
#include <hip/hip_runtime.h>

// NNGLS: y_decor, o_decor, o for N=200000, M=20, MLP 64->256->1.
//
// K1 (mlp_mfma_kernel): split-bf16 MFMA GEMM (x=xh+xl, w1=wh+wl; 3 passes
//     ah*bh + al*bh + ah*bl => ~fp32 accuracy). Wave owns 64 nodes (4 M-tiles
//     of mfma_f32_16x16x32_bf16); w1 staged frag-ordered in LDS (hi+lo, 64KB);
//     layer2 (relu->dot w2) fused via per-lane partials + shfl_xor reduction.
//     UNCHANGED this round (control).
// K2 (solve_kernel): QUAD-SPLIT bordered 21x21 elimination, TEMPLATE-FORCED
//     unrolling. Rounds 2/3 failed because `#pragma unroll` on the 20-step
//     elimination loop was DECLINED by the cost model -> loop var became
//     runtime -> runtime-indexed register array -> whole array demoted to
//     scratch (signature: VGPR 60-128 + GB-scale WRITE_SIZE). Fix: elim_step<K>
//     instantiated 20x explicitly (and build_col<J> 5x) -- every array index
//     is a template constant; the unroller has no say.
//     Layout: lane h=tid&3 owns columns c===h (mod 4); slot j=0..4 holds
//     column 4j+h rows 0..4j+3 (padded; sub-diagonal entries are real
//     symmetric-covariance values, maintained by the same exact row-ops);
//     column 20 replicated on all 4 lanes (rows 0..20) -> f lane-local.
//     Border vector: lanes 0,2 carry y; lanes 1,3 carry o. Per step K:
//     1 shfl pivot broadcast + (19-K) quad shfls gather m[r] from column
//     owners, then each lane updates its own stored rows. Row-ops restricted
//     to stored entries are the textbook full-matrix elimination => upper
//     entries and bv follow bit-identical value paths vs the round-1 kernel.
//     ~830 FMA/lane (vs 2660 monolithic) at 2 waves/SIMD (cap 256, live ~175).

#define MM   20
#define PP   64
#define HH   256
#define EPSF 1e-12f

// flat quad-split storage: slot j (col 4j+h), padded rows 0..4j+3
#define CSE(j, r) csx[2*(j)*((j)+1) + (r)]
#define C20(r)    csx[60 + (r)]

typedef __attribute__((ext_vector_type(8))) short bf16x8;
typedef __attribute__((ext_vector_type(4))) float f32x4;

static __device__ __forceinline__ unsigned short f2bf(float f) {
    unsigned int u = __builtin_bit_cast(unsigned int, f);
    u += 0x7fffu + ((u >> 16) & 1u);          // RNE
    return (unsigned short)(u >> 16);
}
static __device__ __forceinline__ float bf2f(unsigned short h) {
    unsigned int u = ((unsigned int)h) << 16;
    return __builtin_bit_cast(float, u);
}

__global__ __launch_bounds__(256, 2)
void mlp_mfma_kernel(const float* __restrict__ x,
                     const float* __restrict__ w1,
                     const float* __restrict__ b1,
                     const float* __restrict__ w2,
                     const float* __restrict__ b2,
                     float* __restrict__ o_out, int n)
{
    __shared__ __align__(16) short swh[PP * HH];   // 32 KB  w1 hi, frag order
    __shared__ __align__(16) short swl[PP * HH];   // 32 KB  w1 lo
    const int tid = threadIdx.x;

    // ---- stage w1 -> frag-ordered bf16 hi/lo ----
    {
        const int col = tid;                       // 256 cols, one per thread
        const int t = col >> 4, nn = col & 15;
        #pragma unroll
        for (int g = 0; g < 8; ++g) {              // k = g*8 + u
            const int s = g >> 2, q = g & 3;
            bf16x8 hv, lv;
            #pragma unroll
            for (int u = 0; u < 8; ++u) {
                float v = w1[(g * 8 + u) * HH + col];
                unsigned short h = f2bf(v);
                hv[u] = (short)h;
                lv[u] = (short)f2bf(v - bf2f(h));
            }
            const int base = ((((t * 2 + s) * 4 + q) * 16) + nn) * 8;
            *(bf16x8*)&swh[base] = hv;
            *(bf16x8*)&swl[base] = lv;
        }
    }
    __syncthreads();

    const int lane = tid & 63;
    const int wv   = tid >> 6;
    const int nn   = lane & 15;      // A-row (node) / B-col (hidden) / C-col
    const int q    = lane >> 4;      // quad
    const int wb   = blockIdx.x * 256 + wv * 64;   // first node of this wave

    float w2v[16], b1v[16];
    #pragma unroll
    for (int t = 0; t < 16; ++t) {
        w2v[t] = w2[t * 16 + nn];
        b1v[t] = b1[t * 16 + nn];
    }

    // ---- A fragments: 4 M-tiles x 2 k-steps, split hi/lo ----
    bf16x8 ah[4][2], al[4][2];
    #pragma unroll
    for (int mt = 0; mt < 4; ++mt) {
        const int row = wb + mt * 16 + nn;
        #pragma unroll
        for (int s = 0; s < 2; ++s) {
            float v[8];
            if (row < n) {
                const float* xp = x + (size_t)row * PP + s * 32 + q * 8;
                float4 va = *(const float4*)(xp);
                float4 vb = *(const float4*)(xp + 4);
                v[0]=va.x; v[1]=va.y; v[2]=va.z; v[3]=va.w;
                v[4]=vb.x; v[5]=vb.y; v[6]=vb.z; v[7]=vb.w;
            } else {
                #pragma unroll
                for (int u = 0; u < 8; ++u) v[u] = 0.0f;
            }
            bf16x8 h, l;
            #pragma unroll
            for (int u = 0; u < 8; ++u) {
                unsigned short hb = f2bf(v[u]);
                h[u] = (short)hb;
                l[u] = (short)f2bf(v[u] - bf2f(hb));
            }
            ah[mt][s] = h;
            al[mt][s] = l;
        }
    }

    float part[4][4];
    #pragma unroll
    for (int mt = 0; mt < 4; ++mt)
        #pragma unroll
        for (int r = 0; r < 4; ++r) part[mt][r] = 0.0f;

    #pragma unroll
    for (int t = 0; t < 16; ++t) {
        f32x4 acc[4];
        #pragma unroll
        for (int mt = 0; mt < 4; ++mt) acc[mt] = (f32x4)(0.0f);
        #pragma unroll
        for (int s = 0; s < 2; ++s) {
            const int fb = ((((t * 2 + s) * 4 + q) * 16) + nn) * 8;
            bf16x8 bh = *(const bf16x8*)&swh[fb];
            bf16x8 bl = *(const bf16x8*)&swl[fb];
            #pragma unroll
            for (int mt = 0; mt < 4; ++mt) {
                acc[mt] = __builtin_amdgcn_mfma_f32_16x16x32_bf16(ah[mt][s], bh, acc[mt], 0, 0, 0);
                acc[mt] = __builtin_amdgcn_mfma_f32_16x16x32_bf16(al[mt][s], bh, acc[mt], 0, 0, 0);
                acc[mt] = __builtin_amdgcn_mfma_f32_16x16x32_bf16(ah[mt][s], bl, acc[mt], 0, 0, 0);
            }
        }
        #pragma unroll
        for (int mt = 0; mt < 4; ++mt)
            #pragma unroll
            for (int r = 0; r < 4; ++r)
                part[mt][r] = fmaf(fmaxf(acc[mt][r] + b1v[t], 0.0f), w2v[t], part[mt][r]);
    }

    #pragma unroll
    for (int w = 1; w < 16; w <<= 1)
        #pragma unroll
        for (int mt = 0; mt < 4; ++mt)
            #pragma unroll
            for (int r = 0; r < 4; ++r)
                part[mt][r] += __shfl_xor(part[mt][r], w, 64);

    const float bb = b2[0];
    if (nn == 0) {
        #pragma unroll
        for (int mt = 0; mt < 4; ++mt) {
            const int row = wb + mt * 16 + q * 4;   // rows q*4+reg, reg=0..3
            if (row < n) {
                float4 o4 = make_float4(part[mt][0] + bb, part[mt][1] + bb,
                                        part[mt][2] + bb, part[mt][3] + bb);
                *(float4*)&o_out[row] = o4;
            }
        }
    }
}

// ---- build one stored column (template-forced constant indices) ----
template<int J>
static __device__ __forceinline__ void build_col(float* __restrict__ csx,
                                                 const float* __restrict__ px,
                                                 const float* __restrict__ py,
                                                 float cxj, float cyj, int h_,
                                                 float diagA, float c0, float c1)
{
    #pragma unroll
    for (int r = 0; r <= 4*J + 3; ++r) {
        float dx = px[r] - cxj;
        float dy = py[r] - cyj;
        float d  = __builtin_amdgcn_sqrtf(fmaf(dx, dx, fmaf(dy, dy, EPSF)));
        float v  = __builtin_amdgcn_exp2f(fmaf(d, c1, c0));
        v = (r == 4*J + h_) ? diagA : v;           // diagonal of col 4J+h
        CSE(J, r) = v;
    }
}

// ---- one elimination step K (template-forced constant indices) ----
template<int K>
static __device__ __forceinline__ void elim_step(float* __restrict__ csx,
                                                 float* __restrict__ bv,
                                                 int qb)
{
    // pivot (K,K): owner lane K&3, slot K>>2 (padded rows include K)
    float pd = __shfl(CSE(K >> 2, K), qb + (K & 3), 64);
    float rp = __builtin_amdgcn_rcpf(pd);
    rp = rp * (2.0f - pd * rp);                    // Newton refine

    // gather pivot-row multipliers m[r] = a[K][r]*rp from column owners.
    // On owner of column r: entry (K, r) = CSE(r>>2, K)  (K < r <= 4*(r>>2)+3).
    float m_all[21];
    #pragma unroll
    for (int r = K + 1; r <= 19; ++r)
        m_all[r] = __shfl(CSE(r >> 2, K) * rp, qb + (r & 3), 64);
    m_all[20] = C20(K) * rp;                       // col 20 replicated locally

    // row-ops on my stored columns (rows K+1..4j+3)
    #pragma unroll
    for (int j = 0; j < 5; ++j) {
        if (4*j + 3 > K) {                         // compile-time folds
            float pk = CSE(j, K);                  // a[K][c], c = 4j+h
            #pragma unroll
            for (int r = K + 1; r <= 4*j + 3; ++r)
                CSE(j, r) = fmaf(-m_all[r], pk, CSE(j, r));
        }
    }
    // replicated column 20 + border vector
    {
        float p20 = C20(K);
        float bk  = bv[K];
        #pragma unroll
        for (int r = K + 1; r <= 20; ++r) {
            C20(r) = fmaf(-m_all[r], p20, C20(r));
            bv[r]  = fmaf(-m_all[r], bk,  bv[r]);
        }
    }
}

__global__ __launch_bounds__(256, 2)
void solve_kernel(const float* __restrict__ pos,
                  const float* __restrict__ y,
                  const int*   __restrict__ nbr,
                  const float* __restrict__ theta,
                  const float* __restrict__ o_in,
                  float* __restrict__ yd,
                  float* __restrict__ od, int n)
{
    const int tid  = threadIdx.x;
    const int l6   = tid & 63;             // lane within wave
    const int h_   = tid & 3;              // column class this lane owns
    const int i    = (blockIdx.x * 256 + tid) >> 2;   // node (4 lanes share)
    if (i >= n) return;
    const int qb   = l6 & ~3;              // quad base lane

    const float sigma_sq = theta[0];
    const float phi      = theta[1];
    const float tau      = theta[2];
    const float tau_sq   = tau * sigma_sq;

    const float L2E = 1.44269504088896340736f;
    const float c1  = -phi * L2E;                       // exp(-phi*d) = exp2(c1*d)
    const float c0  = __builtin_amdgcn_logf(sigma_sq);  // log2(sigma^2)

    const float sqrtEPS = __builtin_amdgcn_sqrtf(EPSF);
    const float diagA   = __builtin_amdgcn_exp2f(fmaf(sqrtEPS, c1, c0)) + tau_sq;
    const float diagB   = sigma_sq + tau;               // border diagonal

    // ---- neighbor indices (static array, static indices only) ----
    int idx[MM];
    const int4* nb4 = (const int4*)(nbr + (size_t)i * MM);
    #pragma unroll
    for (int k = 0; k < MM / 4; ++k) {
        int4 v = nb4[k];
        idx[4*k] = v.x; idx[4*k+1] = v.y; idx[4*k+2] = v.z; idx[4*k+3] = v.w;
    }

    // row coords (all 21, static-indexed)
    float px[21], py[21];
    const float2* pos2 = (const float2*)pos;
    #pragma unroll
    for (int j = 0; j < MM; ++j) {
        float2 p = pos2[idx[j]];
        px[j] = p.x; py[j] = p.y;
    }
    {
        float2 p = pos2[i];
        px[20] = p.x; py[20] = p.y;
    }

    // my columns' coords: gathered DIRECTLY from nbr/pos (runtime address ok;
    // runtime index into a register array is not).
    float cx[5], cy[5];
    #pragma unroll
    for (int j = 0; j < 5; ++j) {
        int cj = nbr[(size_t)i * MM + 4*j + h_];
        float2 p = pos2[cj];
        cx[j] = p.x; cy[j] = p.y;
    }

    // border vector: lanes 0,2 carry y; lanes 1,3 carry o
    float bv[21];
    {
        const float* src = (h_ & 1) ? o_in : y;
        #pragma unroll
        for (int j = 0; j < MM; ++j) bv[j] = src[idx[j]];
        bv[20] = src[i];
    }

    // ---- build my columns (padded) + replicated column 20 ----
    float csx[81];
    build_col<0>(csx, px, py, cx[0], cy[0], h_, diagA, c0, c1);
    build_col<1>(csx, px, py, cx[1], cy[1], h_, diagA, c0, c1);
    build_col<2>(csx, px, py, cx[2], cy[2], h_, diagA, c0, c1);
    build_col<3>(csx, px, py, cx[3], cy[3], h_, diagA, c0, c1);
    build_col<4>(csx, px, py, cx[4], cy[4], h_, diagA, c0, c1);
    #pragma unroll
    for (int r = 0; r < 20; ++r) {
        float dx = px[r] - px[20];
        float dy = py[r] - py[20];
        float d  = __builtin_amdgcn_sqrtf(fmaf(dx, dx, fmaf(dy, dy, EPSF)));
        C20(r)   = __builtin_amdgcn_exp2f(fmaf(d, c1, c0));
    }
    C20(20) = diagB;

    // ---- 20 elimination steps, quad-cooperative, template-forced unroll ----
    elim_step< 0>(csx, bv, qb);  elim_step< 1>(csx, bv, qb);
    elim_step< 2>(csx, bv, qb);  elim_step< 3>(csx, bv, qb);
    elim_step< 4>(csx, bv, qb);  elim_step< 5>(csx, bv, qb);
    elim_step< 6>(csx, bv, qb);  elim_step< 7>(csx, bv, qb);
    elim_step< 8>(csx, bv, qb);  elim_step< 9>(csx, bv, qb);
    elim_step<10>(csx, bv, qb);  elim_step<11>(csx, bv, qb);
    elim_step<12>(csx, bv, qb);  elim_step<13>(csx, bv, qb);
    elim_step<14>(csx, bv, qb);  elim_step<15>(csx, bv, qb);
    elim_step<16>(csx, bv, qb);  elim_step<17>(csx, bv, qb);
    elim_step<18>(csx, bv, qb);  elim_step<19>(csx, bv, qb);

    // f = a[20][20], replicated on every lane
    float f  = C20(20);
    float is = __builtin_amdgcn_rsqf(f);
    is = is * fmaf(-0.5f * f * is, is, 1.5f);

    if (h_ == 0)      yd[i] = bv[20] * is;   // lanes 0/2 carry y
    else if (h_ == 1) od[i] = bv[20] * is;   // lanes 1/3 carry o
}

extern "C" void kernel_launch(void* const* d_in, const int* in_sizes, int n_in,
                              void* d_out, int out_size, void* d_ws, size_t ws_size,
                              hipStream_t stream)
{
    const float* x     = (const float*)d_in[0];
    const float* pos   = (const float*)d_in[1];
    const float* y     = (const float*)d_in[2];
    const int*   nbr   = (const int*)  d_in[3];
    const float* theta = (const float*)d_in[4];
    const float* w1    = (const float*)d_in[5];
    const float* b1    = (const float*)d_in[6];
    const float* w2    = (const float*)d_in[7];
    const float* b2    = (const float*)d_in[8];

    const int n = in_sizes[2];                 // N
    float* out = (float*)d_out;
    float* yd = out;
    float* od = out + (size_t)n;
    float* oo = out + 2 * (size_t)n;

    mlp_mfma_kernel<<<(n + 255) / 256, 256, 0, stream>>>(x, w1, b1, w2, b2, oo, n);
    // 64 nodes per 256-thread block (4 lanes per node)
    solve_kernel<<<(n + 63) / 64, 256, 0, stream>>>(pos, y, nbr, theta, oo, yd, od, n);
}

// Round 5
// 215.119 us; speedup vs baseline: 4.6597x; 1.4544x over previous
//
#include <hip/hip_runtime.h>

// NNGLS: y_decor, o_decor, o for N=200000, M=20, MLP 64->256->1.
//
// K1 (mlp_mfma_kernel): split-bf16 MFMA GEMM -- UNCHANGED this round (control).
// K2 (solve_kernel): QUAD-SPLIT elimination in the ROUND-0 CODE SHAPE.
//     Lessons: r2/r3 (#pragma unroll declined -> runtime k -> scratch) and
//     r4 (template-forced indices BUT array passed by pointer to helpers ->
//     SROA never promoted -> 81 floats/lane round-tripped scratch, VGPR=128,
//     WRITE 280MB). The ONE proven-resident pattern is round-0's: arrays in
//     ONE function scope, rolled `#pragma unroll 1` k-loop, switch(k) copying
//     pivot data to fixed regs with literal indices, full-range static masked
//     updates. This kernel = that shape + quad-split layout:
//       lane h=tid&3 owns cols c===h (mod4); slot j stores col 4j+h rows
//       0..4j+3 (padding: for any r>K the owner of col r stores row K);
//       col 20 replicated (21) -> 81 floats/lane (vs 231 monolithic).
//     Per step k: case K copies pk[j]=a[K][col_j] (literal idx; dead slots
//     =0.0f), p20=C20(K), pbv=bv[K], and pivot pd via ds_swizzle quad-perm
//     with LITERAL pattern. Outside: rp=refined rcp; mv[j]=(4j+h>k)?pk[j]*rp
//     :0 (owner mask === r>k); 20 macro'd ds_swizzle quad-broadcasts gather
//     m[r]; masked full-range FMAs on slots/c20/bv (frozen rows: exact
//     fma(-0,*,a) no-ops, identical to round 0 -> bit-identical results).
//     ~123 FMA + 21 DS/step, live ~180 regs < 256 cap (launch_bounds(256,2)
//     => 2 waves/SIMD), loop body ~2.7KB => I$-resident.

#define MM   20
#define PP   64
#define HH   256
#define EPSF 1e-12f

// quad-split storage: slot j (col 4j+h), rows 0..4j+3 at offset 2j(j+1);
// replicated col 20 at offset 60.
#define CSE(j, r) csx[2*(j)*((j)+1) + (r)]
#define C20(r)    csx[60 + (r)]

typedef __attribute__((ext_vector_type(8))) short bf16x8;
typedef __attribute__((ext_vector_type(4))) float f32x4;

static __device__ __forceinline__ unsigned short f2bf(float f) {
    unsigned int u = __builtin_bit_cast(unsigned int, f);
    u += 0x7fffu + ((u >> 16) & 1u);          // RNE
    return (unsigned short)(u >> 16);
}
static __device__ __forceinline__ float bf2f(unsigned short h) {
    unsigned int u = ((unsigned int)h) << 16;
    return __builtin_bit_cast(float, u);
}

__global__ __launch_bounds__(256, 2)
void mlp_mfma_kernel(const float* __restrict__ x,
                     const float* __restrict__ w1,
                     const float* __restrict__ b1,
                     const float* __restrict__ w2,
                     const float* __restrict__ b2,
                     float* __restrict__ o_out, int n)
{
    __shared__ __align__(16) short swh[PP * HH];   // 32 KB  w1 hi, frag order
    __shared__ __align__(16) short swl[PP * HH];   // 32 KB  w1 lo
    const int tid = threadIdx.x;

    // ---- stage w1 -> frag-ordered bf16 hi/lo ----
    {
        const int col = tid;                       // 256 cols, one per thread
        const int t = col >> 4, nn = col & 15;
        #pragma unroll
        for (int g = 0; g < 8; ++g) {              // k = g*8 + u
            const int s = g >> 2, q = g & 3;
            bf16x8 hv, lv;
            #pragma unroll
            for (int u = 0; u < 8; ++u) {
                float v = w1[(g * 8 + u) * HH + col];
                unsigned short h = f2bf(v);
                hv[u] = (short)h;
                lv[u] = (short)f2bf(v - bf2f(h));
            }
            const int base = ((((t * 2 + s) * 4 + q) * 16) + nn) * 8;
            *(bf16x8*)&swh[base] = hv;
            *(bf16x8*)&swl[base] = lv;
        }
    }
    __syncthreads();

    const int lane = tid & 63;
    const int wv   = tid >> 6;
    const int nn   = lane & 15;      // A-row (node) / B-col (hidden) / C-col
    const int q    = lane >> 4;      // quad
    const int wb   = blockIdx.x * 256 + wv * 64;   // first node of this wave

    float w2v[16], b1v[16];
    #pragma unroll
    for (int t = 0; t < 16; ++t) {
        w2v[t] = w2[t * 16 + nn];
        b1v[t] = b1[t * 16 + nn];
    }

    // ---- A fragments: 4 M-tiles x 2 k-steps, split hi/lo ----
    bf16x8 ah[4][2], al[4][2];
    #pragma unroll
    for (int mt = 0; mt < 4; ++mt) {
        const int row = wb + mt * 16 + nn;
        #pragma unroll
        for (int s = 0; s < 2; ++s) {
            float v[8];
            if (row < n) {
                const float* xp = x + (size_t)row * PP + s * 32 + q * 8;
                float4 va = *(const float4*)(xp);
                float4 vb = *(const float4*)(xp + 4);
                v[0]=va.x; v[1]=va.y; v[2]=va.z; v[3]=va.w;
                v[4]=vb.x; v[5]=vb.y; v[6]=vb.z; v[7]=vb.w;
            } else {
                #pragma unroll
                for (int u = 0; u < 8; ++u) v[u] = 0.0f;
            }
            bf16x8 h, l;
            #pragma unroll
            for (int u = 0; u < 8; ++u) {
                unsigned short hb = f2bf(v[u]);
                h[u] = (short)hb;
                l[u] = (short)f2bf(v[u] - bf2f(hb));
            }
            ah[mt][s] = h;
            al[mt][s] = l;
        }
    }

    float part[4][4];
    #pragma unroll
    for (int mt = 0; mt < 4; ++mt)
        #pragma unroll
        for (int r = 0; r < 4; ++r) part[mt][r] = 0.0f;

    #pragma unroll
    for (int t = 0; t < 16; ++t) {
        f32x4 acc[4];
        #pragma unroll
        for (int mt = 0; mt < 4; ++mt) acc[mt] = (f32x4)(0.0f);
        #pragma unroll
        for (int s = 0; s < 2; ++s) {
            const int fb = ((((t * 2 + s) * 4 + q) * 16) + nn) * 8;
            bf16x8 bh = *(const bf16x8*)&swh[fb];
            bf16x8 bl = *(const bf16x8*)&swl[fb];
            #pragma unroll
            for (int mt = 0; mt < 4; ++mt) {
                acc[mt] = __builtin_amdgcn_mfma_f32_16x16x32_bf16(ah[mt][s], bh, acc[mt], 0, 0, 0);
                acc[mt] = __builtin_amdgcn_mfma_f32_16x16x32_bf16(al[mt][s], bh, acc[mt], 0, 0, 0);
                acc[mt] = __builtin_amdgcn_mfma_f32_16x16x32_bf16(ah[mt][s], bl, acc[mt], 0, 0, 0);
            }
        }
        #pragma unroll
        for (int mt = 0; mt < 4; ++mt)
            #pragma unroll
            for (int r = 0; r < 4; ++r)
                part[mt][r] = fmaf(fmaxf(acc[mt][r] + b1v[t], 0.0f), w2v[t], part[mt][r]);
    }

    #pragma unroll
    for (int w = 1; w < 16; w <<= 1)
        #pragma unroll
        for (int mt = 0; mt < 4; ++mt)
            #pragma unroll
            for (int r = 0; r < 4; ++r)
                part[mt][r] += __shfl_xor(part[mt][r], w, 64);

    const float bb = b2[0];
    if (nn == 0) {
        #pragma unroll
        for (int mt = 0; mt < 4; ++mt) {
            const int row = wb + mt * 16 + q * 4;   // rows q*4+reg, reg=0..3
            if (row < n) {
                float4 o4 = make_float4(part[mt][0] + bb, part[mt][1] + bb,
                                        part[mt][2] + bb, part[mt][3] + bb);
                *(float4*)&o_out[row] = o4;
            }
        }
    }
}

// quad broadcast of lane (PAT) within each 4-lane group, literal pattern
#define QSWZ(v, s) __builtin_bit_cast(float, __builtin_amdgcn_ds_swizzle( \
    __builtin_bit_cast(int, (v)), 0x8000 | (0x55 * (s))))

__global__ __launch_bounds__(256, 2)
void solve_kernel(const float* __restrict__ pos,
                  const float* __restrict__ y,
                  const int*   __restrict__ nbr,
                  const float* __restrict__ theta,
                  const float* __restrict__ o_in,
                  float* __restrict__ yd,
                  float* __restrict__ od, int n)
{
    const int tid  = threadIdx.x;
    const int h_   = tid & 3;                         // column class
    const int i    = blockIdx.x * 64 + (tid >> 2);    // node (4 lanes/node)
    if (i >= n) return;

    const float sigma_sq = theta[0];
    const float phi      = theta[1];
    const float tau      = theta[2];
    const float tau_sq   = tau * sigma_sq;

    const float L2E = 1.44269504088896340736f;
    const float c1  = -phi * L2E;                       // exp(-phi*d) = exp2(c1*d)
    const float c0  = __builtin_amdgcn_logf(sigma_sq);  // log2(sigma^2)

    const float sqrtEPS = __builtin_amdgcn_sqrtf(EPSF);
    const float diagA   = __builtin_amdgcn_exp2f(fmaf(sqrtEPS, c1, c0)) + tau_sq;
    const float diagB   = sigma_sq + tau;               // border diagonal

    // ---- neighbor indices (static indices only) ----
    int idx[MM];
    const int4* nb4 = (const int4*)(nbr + (size_t)i * MM);
    #pragma unroll
    for (int k = 0; k < MM / 4; ++k) {
        int4 v = nb4[k];
        idx[4*k] = v.x; idx[4*k+1] = v.y; idx[4*k+2] = v.z; idx[4*k+3] = v.w;
    }

    // row coords (all 21, static-indexed)
    float px[21], py[21];
    const float2* pos2 = (const float2*)pos;
    #pragma unroll
    for (int j = 0; j < MM; ++j) {
        float2 p = pos2[idx[j]];
        px[j] = p.x; py[j] = p.y;
    }
    {
        float2 p = pos2[i];
        px[20] = p.x; py[20] = p.y;
    }

    // my columns' coords: re-gathered from nbr/pos (runtime ADDRESS is fine;
    // runtime index into a register array is not).
    float cx[5], cy[5];
    #pragma unroll
    for (int j = 0; j < 5; ++j) {
        int cj = nbr[(size_t)i * MM + 4*j + h_];
        float2 p = pos2[cj];
        cx[j] = p.x; cy[j] = p.y;
    }

    // border vector: lanes 0,2 carry y; lanes 1,3 carry o
    float bv[21];
    {
        const float* src = (h_ & 1) ? o_in : y;
        #pragma unroll
        for (int j = 0; j < MM; ++j) bv[j] = src[idx[j]];
        bv[20] = src[i];
    }

    // ---- build my slots (rows 0..4j+3 of col 4j+h) + replicated col 20 ----
    float csx[81];
    #pragma unroll
    for (int j = 0; j < 5; ++j) {
        #pragma unroll
        for (int r = 0; r <= 4*j + 3; ++r) {
            float dx = px[r] - cx[j];
            float dy = py[r] - cy[j];
            float d  = __builtin_amdgcn_sqrtf(fmaf(dx, dx, fmaf(dy, dy, EPSF)));
            float v  = __builtin_amdgcn_exp2f(fmaf(d, c1, c0));
            v = (r == 4*j + h_) ? diagA : v;       // diagonal of col 4j+h
            CSE(j, r) = v;
        }
    }
    #pragma unroll
    for (int r = 0; r < 20; ++r) {
        float dx = px[r] - px[20];
        float dy = py[r] - py[20];
        float d  = __builtin_amdgcn_sqrtf(fmaf(dx, dx, fmaf(dy, dy, EPSF)));
        C20(r)   = __builtin_amdgcn_exp2f(fmaf(d, c1, c0));
    }
    C20(20) = diagB;

    // ---- 20 elimination steps, ROLLED loop + switch (round-0 shape) ----
    float pk[5], p20, pbv, pd;
    #pragma unroll 1
    for (int k = 0; k < 20; ++k) {
        switch (k) {
#define CASEK(K) case K: {                                                 \
            _Pragma("unroll")                                              \
            for (int j = 0; j < 5; ++j)                                    \
                pk[j] = (4*j + 3 >= (K)) ? CSE(j, (K)) : 0.0f;             \
            p20 = C20(K); pbv = bv[K];                                     \
            pd  = QSWZ(pk[(K) >> 2], (K) & 3);                             \
        } break;
        CASEK(0)  CASEK(1)  CASEK(2)  CASEK(3)  CASEK(4)
        CASEK(5)  CASEK(6)  CASEK(7)  CASEK(8)  CASEK(9)
        CASEK(10) CASEK(11) CASEK(12) CASEK(13) CASEK(14)
        CASEK(15) CASEK(16) CASEK(17) CASEK(18) CASEK(19)
#undef CASEK
        default: break;
        }
        float rp = __builtin_amdgcn_rcpf(pd);
        rp = rp * (2.0f - pd * rp);                 // Newton refine

        // my column-as-row multipliers; owner mask (4j+h > k) === (row > k)
        float mv[5];
        #pragma unroll
        for (int j = 0; j < 5; ++j)
            mv[j] = (4*j + h_ > k) ? pk[j] * rp : 0.0f;

        // gather m[r] = a[k][r]*rp from column owners (literal quad patterns)
        float mall[21];
#define GATHER(R) mall[R] = QSWZ(mv[(R) >> 2], (R) & 3);
        GATHER(0)  GATHER(1)  GATHER(2)  GATHER(3)  GATHER(4)
        GATHER(5)  GATHER(6)  GATHER(7)  GATHER(8)  GATHER(9)
        GATHER(10) GATHER(11) GATHER(12) GATHER(13) GATHER(14)
        GATHER(15) GATHER(16) GATHER(17) GATHER(18) GATHER(19)
#undef GATHER
        mall[20] = p20 * rp;                        // col 20 local; 20 > k

        // masked full-range updates (rows r<=k: exact fma(-0,*,a) no-ops)
        #pragma unroll
        for (int j = 0; j < 5; ++j) {
            float pkj = pk[j];
            #pragma unroll
            for (int r = 0; r <= 4*j + 3; ++r)
                CSE(j, r) = fmaf(-mall[r], pkj, CSE(j, r));
        }
        #pragma unroll
        for (int r = 0; r <= 20; ++r) {
            C20(r) = fmaf(-mall[r], p20, C20(r));
            bv[r]  = fmaf(-mall[r], pbv, bv[r]);
        }
    }

    // f = a[20][20], replicated on every lane
    float f  = C20(20);
    float is = __builtin_amdgcn_rsqf(f);
    is = is * fmaf(-0.5f * f * is, is, 1.5f);

    if (h_ == 0)      yd[i] = bv[20] * is;   // lanes 0/2 carry y
    else if (h_ == 1) od[i] = bv[20] * is;   // lanes 1/3 carry o
}

extern "C" void kernel_launch(void* const* d_in, const int* in_sizes, int n_in,
                              void* d_out, int out_size, void* d_ws, size_t ws_size,
                              hipStream_t stream)
{
    const float* x     = (const float*)d_in[0];
    const float* pos   = (const float*)d_in[1];
    const float* y     = (const float*)d_in[2];
    const int*   nbr   = (const int*)  d_in[3];
    const float* theta = (const float*)d_in[4];
    const float* w1    = (const float*)d_in[5];
    const float* b1    = (const float*)d_in[6];
    const float* w2    = (const float*)d_in[7];
    const float* b2    = (const float*)d_in[8];

    const int n = in_sizes[2];                 // N
    float* out = (float*)d_out;
    float* yd = out;
    float* od = out + (size_t)n;
    float* oo = out + 2 * (size_t)n;

    mlp_mfma_kernel<<<(n + 255) / 256, 256, 0, stream>>>(x, w1, b1, w2, b2, oo, n);
    // 64 nodes per 256-thread block (4 lanes per node)
    solve_kernel<<<(n + 63) / 64, 256, 0, stream>>>(pos, y, nbr, theta, oo, yd, od, n);
}